// Round 6
// baseline (327.315 us; speedup 1.0000x reference)
//
#include <hip/hip_runtime.h>
#include <hip/hip_bf16.h>

#define Bq 4
#define Sq 2048
#define Dq 1024
#define Hq 16
#define HDq 64
#define Mq (Bq*Sq)   // 8192

typedef unsigned short u16;
typedef __attribute__((ext_vector_type(8))) __bf16 b16x8;
typedef __attribute__((ext_vector_type(4))) float f32x4;
typedef __attribute__((ext_vector_type(4))) unsigned int u32x4;

__device__ inline float bf2f(u16 h){ union{unsigned u; float f;} v; v.u = ((unsigned)h)<<16; return v.f; }
__device__ inline u16 f2bf(float f){ union{float f; unsigned u;} v; v.f=f; unsigned r = v.u + 0x7FFFu + ((v.u>>16)&1u); return (u16)(r>>16); }
__device__ inline u16 truncbf(float f){ union{float f; unsigned u;} v; v.f=f; return (u16)(v.u>>16); }
__device__ inline float ld_elem(const void* p, size_t i, int isf32){
  return isf32 ? ((const float*)p)[i] : bf2f(((const u16*)p)[i]);
}
// async global->LDS, 16B per lane; LDS dest must be wave-uniform-base + lane*16
__device__ inline void ld16(const u16* g, u16* l){
  __builtin_amdgcn_global_load_lds((const __attribute__((address_space(1))) void*)g,
                                   (__attribute__((address_space(3))) void*)l, 16, 0, 0);
}
#define LDSLOAD(x)  __hip_atomic_load(&(x), __ATOMIC_ACQUIRE, __HIP_MEMORY_SCOPE_WORKGROUP)
#define LDSSTORE(x,v) __hip_atomic_store(&(x), (v), __ATOMIC_RELEASE, __HIP_MEMORY_SCOPE_WORKGROUP)

#if __has_builtin(__builtin_amdgcn_exp2f)
#define EXP2(x) __builtin_amdgcn_exp2f(x)
#else
#define EXP2(x) __expf((x)*0.69314718056f)
#endif
// 0.125 (1/sqrt(64)) * log2(e): softmax in exp2 domain, no max subtraction
#define SCALE_LOG2E 0.18033688011112042f

// ---- dtype probe: fp32 buffers read as u16 halves -> huge bf16 exponents
__global__ void detect_dtype(const unsigned* __restrict__ x, int* __restrict__ flag){
  __shared__ int cnt;
  if(threadIdx.x==0) cnt=0;
  __syncthreads();
  int local=0;
  for(int i=threadIdx.x;i<2048;i+=256){
    unsigned w = x[i];
    if(((w>>7)&0xFFu)>=0x90u) local++;
    if(((w>>23)&0xFFu)>=0x90u) local++;
  }
  atomicAdd(&cnt, local);
  __syncthreads();
  if(threadIdx.x==0) *flag = (cnt>64) ? 1 : 0;
}

// ---- x -> canonical bf16
__global__ __launch_bounds__(256) void convert_x(const void* __restrict__ x, u16* __restrict__ xc,
                                                 const int* __restrict__ flag, int n){
  const int f = *flag;
  int i = (blockIdx.x*256 + threadIdx.x)*8;
  if(i>=n) return;
  if(f){
    const float* xf=(const float*)x;
    #pragma unroll
    for(int j=0;j<8;j++) xc[i+j] = f2bf(xf[i+j]);
  } else {
    *(u32x4*)&xc[i] = *(const u32x4*)((const u16*)x + i);
  }
}

// ---- weight transpose+convert: W[k][n] -> WT[n][k] bf16
__global__ __launch_bounds__(256) void transpose_w(
    const void* __restrict__ W0, const void* __restrict__ W1,
    const void* __restrict__ W2, const void* __restrict__ W3,
    u16* __restrict__ T0, u16* __restrict__ T1,
    u16* __restrict__ T2, u16* __restrict__ T3,
    const int* __restrict__ flag){
  __shared__ u16 tile[64][65];
  const int f = *flag;
  const int z = blockIdx.z;
  const void* src = (z==0)?W0:(z==1)?W1:(z==2)?W2:W3;
  u16*       dst = (z==0)?T0:(z==1)?T1:(z==2)?T2:T3;
  const int t = threadIdx.x;
  const int k0 = blockIdx.x*64, n0 = blockIdx.y*64;
  #pragma unroll
  for(int r=0;r<16;r++){
    int row = r*4 + (t>>6), col = t&63;
    tile[row][col] = f2bf(ld_elem(src, (size_t)(k0+row)*Dq + n0 + col, f));
  }
  __syncthreads();
  #pragma unroll
  for(int r=0;r<16;r++){
    int row = r*4 + (t>>6), col = t&63;
    dst[(size_t)(n0+row)*Dq + k0 + col] = tile[col][row];
  }
}

// ---------------- producer-consumer GEMM: C = A * Bt^T ----------------
// 512 threads: waves 0-3 compute 128x128 (4x4 mfma_16x16x32 each), waves 4-7 stage
// a 3-deep LDS ring (BK=32). No __syncthreads in the K-loop: producers use
// fine-grained s_waitcnt vmcnt(4) (AITER-style, never 0 mid-loop) + release flags;
// consumers acquire-poll. Only producer waves absorb DMA latency.
// Swizzle: group g (4x16B per 64B row) stored at phys g^((row>>1)&3) -> b128 frag
// reads hit 8 distinct bank-groups (zero-conflict structure, verified r5).
// MODE 0: A=xc, Bt=[WqT;WkT;WvT] (N=3072); epilogue splits z=n>>10 -> Q/K/VT layouts.
// MODE 1: out-proj + bias, fp32 or bf16 out per dtype flag.
template<int MODE>
__global__ __launch_bounds__(512) void gemm128(
    const u16* __restrict__ A, const u16* __restrict__ Bt,
    u16* __restrict__ O0, u16* __restrict__ O1, u16* __restrict__ O2,
    void* __restrict__ Og, const void* __restrict__ bias, const int* __restrict__ flag){
  __shared__ u16 As[3][128*32];
  __shared__ u16 Bs[3][128*32];
  __shared__ int pflag[3][4];   // producer staged-count per stage
  __shared__ int cdone[3][4];   // consumer done-count per stage
  const int t = threadIdx.x;
  const int lane = t & 63, wave = t >> 6;
  const int quad = lane >> 4, l16 = lane & 15;
  const int m0 = blockIdx.y*128, n0 = blockIdx.x*128;
  const int NK = Dq/32;         // 32 k-steps

  if(t < 12){ pflag[t>>2][t&3] = 0; cdone[t>>2][t&3] = 0; }
  __syncthreads();

  if(wave >= 4){
    // ---- producer ----
    const int pw = wave - 4;
    int s = 0, ps = 2;
    for(int k=0;k<NK;k++){
      if(k>=3){
        #pragma unroll
        for(int c=0;c<4;c++)
          while(LDSLOAD(cdone[s][c]) < k-2) __builtin_amdgcn_s_sleep(1);
      }
      #pragma unroll
      for(int r=0;r<2;r++){
        int idx = pw*64 + lane + (r<<8);       // 0..511 slots (16B)
        int row = idx>>2, g = idx&3;
        int csw = (((g ^ (row>>1)) & 3) << 3); // swizzled source col (elems)
        ld16(&A [(size_t)(m0+row)*Dq + k*32 + csw], &As[s][idx*8]);
        ld16(&Bt[(size_t)(n0+row)*Dq + k*32 + csw], &Bs[s][idx*8]);
      }
      if(k>=1){
        __builtin_amdgcn_s_waitcnt(0x0F74);    // vmcnt(4): stage k-1's 4 loads done
        LDSSTORE(pflag[ps][pw], k);
      }
      ps = s; s = (s==2)?0:s+1;
    }
    __builtin_amdgcn_s_waitcnt(0x0F70);        // vmcnt(0): flush last stage
    LDSSTORE(pflag[ps][pw], NK);
  } else {
    // ---- consumer ----
    const int wr = wave >> 1, wc = wave & 1;
    f32x4 acc[4][4] = {};
    int s = 0;
    for(int k=0;k<NK;k++){
      #pragma unroll
      for(int p=0;p<4;p++)
        while(LDSLOAD(pflag[s][p]) < k+1) __builtin_amdgcn_s_sleep(1);
      b16x8 af[4], bfr[4];
      #pragma unroll
      for(int i=0;i<4;i++){
        int row = wr*64 + i*16 + l16;
        af[i] = *(const b16x8*)&As[s][row*32 + (((quad ^ (row>>1))&3)<<3)];
      }
      #pragma unroll
      for(int j=0;j<4;j++){
        int row = wc*64 + j*16 + l16;
        bfr[j] = *(const b16x8*)&Bs[s][row*32 + (((quad ^ (row>>1))&3)<<3)];
      }
      #pragma unroll
      for(int i=0;i<4;i++)
        #pragma unroll
        for(int j=0;j<4;j++)
          acc[i][j] = __builtin_amdgcn_mfma_f32_16x16x32_bf16(af[i], bfr[j], acc[i][j], 0,0,0);
      LDSSTORE(cdone[s][wave], k+1);
      s = (s==2)?0:s+1;
    }
    // epilogue (consumers only)
    const int f = (MODE==1) ? *flag : 0;
    #pragma unroll
    for(int i=0;i<4;i++){
      #pragma unroll
      for(int j=0;j<4;j++){
        int n = n0 + wc*64 + j*16 + l16;
        #pragma unroll
        for(int r=0;r<4;r++){
          int m = m0 + wr*64 + i*16 + quad*4 + r;   // C/D: row=quad*4+reg, col=l16
          float c = acc[i][j][r];
          if (MODE==1){
            float c2 = c + ld_elem(bias, n, f);
            if (f) ((float*)Og)[(size_t)m*Dq + n] = c2;
            else   ((u16*)Og)[(size_t)m*Dq + n]   = f2bf(c2);
          } else {
            int z = n >> 10, nn = n & 1023;
            int b = m >> 11, ss = m & 2047;
            int h = nn >> 6, hd = nn & 63;
            if (z==0)      O0[(((size_t)(b*Hq + h))*Sq + ss)*HDq + hd] = f2bf(c);
            else if (z==1) O1[(((size_t)(b*Hq + h))*Sq + ss)*HDq + hd] = f2bf(c);
            else           O2[(((size_t)(b*Hq + h))*HDq + hd)*Sq + ss] = f2bf(c);
          }
        }
      }
    }
  }
}

// ---------------- flash attention v4 (unchanged from r5) ----------------
__global__ __launch_bounds__(256) void flash_attn(
    const u16* __restrict__ Q, const u16* __restrict__ K,
    const u16* __restrict__ VT, u16* __restrict__ C){
  __shared__ u16 Kt[128*64];    // [key][hd], 8 groups/row swizzled
  __shared__ u16 Vt[64*128];    // [hd][key], 16 groups/row swizzled
  __shared__ u16 Pl[4][16][72]; // per-wave P round-trip (C-layout -> A-layout)
  const int t = threadIdx.x;
  const int lane = t&63, wave = t>>6, quad = lane>>4, l16 = lane&15;
  const int p = blockIdx.x, bh = blockIdx.y;
  const int b = bh >> 4, h = bh & 15;
  const int qt[2] = { p, 31 - p };
  int nk[2];
  #pragma unroll
  for(int tt=0;tt<2;tt++){ int v = qt[tt]+2; nk[tt] = (v<32)?v:32; }
  const int nrounds = (nk[1]+1)>>1;
  const u16* Qh = Q  + (size_t)bh*Sq*HDq;
  const u16* Kh = K  + (size_t)bh*Sq*HDq;
  const u16* Vh = VT + (size_t)bh*HDq*Sq;

  b16x8 aq[2][2];
  #pragma unroll
  for(int tt=0;tt<2;tt++){
    const u16* qp = Qh + (size_t)(qt[tt]*64 + wave*16 + l16)*HDq + quad*8;
    aq[tt][0] = *(const b16x8*)qp;
    aq[tt][1] = *(const b16x8*)(qp + 32);
  }
  b16x8 vone;
  #pragma unroll
  for(int i=0;i<8;i++) vone[i] = (__bf16)1.0f;

  const f32x4 fzero = {0.f,0.f,0.f,0.f};
  f32x4 Oa[2][4]; f32x4 lacc[2];
  #pragma unroll
  for(int tt=0;tt<2;tt++){ lacc[tt]=fzero; for(int j=0;j<4;j++) Oa[tt][j]=fzero; }

  for(int kt2=0; kt2<nrounds; kt2++){
    __syncthreads();
    #pragma unroll
    for(int r=0;r<4;r++){
      int idx = t + (r<<8);            // K slots 0..1023
      int row = idx>>3, g = idx&7;
      int csw = (g ^ (row&7))<<3;
      ld16(Kh + (size_t)(kt2*128+row)*HDq + csw, Kt + idx*8);
    }
    #pragma unroll
    for(int r=0;r<4;r++){
      int idx = t + (r<<8);            // V slots 0..1023
      int row = idx>>4, g = idx&15;    // 64 hd-rows x 16 groups
      int csw = (g ^ (row&15))<<3;
      ld16(Vh + (size_t)row*Sq + (size_t)kt2*128 + csw, Vt + idx*8);
    }
    __syncthreads();

    #pragma unroll
    for(int half=0; half<2; half++){
      const int kt = kt2*2 + half;
      #pragma unroll
      for(int tt=0;tt<2;tt++){
        if (kt >= nk[tt]) continue;            // wave-uniform skip
        const int qq0 = qt[tt]*64;
        f32x4 sc[4];
        #pragma unroll
        for(int jn=0;jn<4;jn++){
          int krow = half*64 + jn*16 + l16;
          const u16* kp = &Kt[krow*64];
          f32x4 s = fzero;
          b16x8 bk0 = *(const b16x8*)&kp[((quad     ^ (krow&7))<<3)];
          b16x8 bk1 = *(const b16x8*)&kp[(((quad+4) ^ (krow&7))<<3)];
          s = __builtin_amdgcn_mfma_f32_16x16x32_bf16(aq[tt][0], bk0, s, 0,0,0);
          s = __builtin_amdgcn_mfma_f32_16x16x32_bf16(aq[tt][1], bk1, s, 0,0,0);
          sc[jn] = s;
        }
        const int qbase = qq0 + wave*16 + quad*4;
        #pragma unroll
        for(int jn=0;jn<4;jn++){
          int kg = kt*64 + jn*16 + l16;
          #pragma unroll
          for(int r=0;r<4;r++){
            float sv = sc[jn][r]*SCALE_LOG2E;
            if (kg > qbase + r + 1) sv = -__builtin_inff();   // tril(k=1): key <= q+1
            Pl[wave][quad*4+r][jn*16+l16] = truncbf(EXP2(sv));
          }
        }
        #pragma unroll
        for(int ks=0;ks<2;ks++){
          b16x8 ap = *(const b16x8*)&Pl[wave][l16][ks*32 + quad*8];
          int glog = half*8 + ks*4 + quad;
          #pragma unroll
          for(int jd=0;jd<4;jd++){
            int hd = jd*16 + l16;
            b16x8 bv = *(const b16x8*)&Vt[hd*128 + ((glog ^ (hd&15))<<3)];
            Oa[tt][jd] = __builtin_amdgcn_mfma_f32_16x16x32_bf16(ap, bv, Oa[tt][jd], 0,0,0);
          }
          lacc[tt] = __builtin_amdgcn_mfma_f32_16x16x32_bf16(ap, vone, lacc[tt], 0,0,0);
        }
      }
    }
  }
  #pragma unroll
  for(int tt=0;tt<2;tt++){
    const int qq0 = qt[tt]*64;
    #pragma unroll
    for(int r=0;r<4;r++){
      int s = qq0 + wave*16 + quad*4 + r;
      float inv = 1.0f / lacc[tt][r];
      #pragma unroll
      for(int jd=0;jd<4;jd++)
        C[((size_t)(b*Sq + s))*Dq + h*HDq + jd*16 + l16] = f2bf(Oa[tt][jd][r]*inv);
    }
  }
}

// ---------------- launch ----------------
extern "C" void kernel_launch(void* const* d_in, const int* in_sizes, int n_in,
                              void* d_out, int out_size, void* d_ws, size_t ws_size,
                              hipStream_t stream){
  const void* x  = d_in[0];
  const void* Wq = d_in[1];
  const void* Wk = d_in[2];
  const void* Wv = d_in[3];
  const void* Wo = d_in[4];
  const void* bo = d_in[5];

  char* ws = (char*)d_ws;
  size_t off = 0;
  auto wsalloc = [&](size_t bytes)->void*{
    void* p = ws + off; off += (bytes + 255) & ~(size_t)255; return p;
  };
  int* flag = (int*)wsalloc(256);
  // WqT/WkT/WvT contiguous: gemm<0> sees one [3072][1024] B^T matrix
  u16* WqT = (u16*)wsalloc((size_t)Dq*Dq*2);
  u16* WkT = (u16*)wsalloc((size_t)Dq*Dq*2);
  u16* WvT = (u16*)wsalloc((size_t)Dq*Dq*2);
  u16* WoT = (u16*)wsalloc((size_t)Dq*Dq*2);
  u16* xc  = (u16*)wsalloc((size_t)Mq*Dq*2);
  u16* Qb  = (u16*)wsalloc((size_t)Mq*Dq*2);   // [b,h,s,hd]
  u16* Kb  = (u16*)wsalloc((size_t)Mq*Dq*2);   // [b,h,s,hd]
  u16* VTb = (u16*)wsalloc((size_t)Mq*Dq*2);   // [b,h,hd,s]
  u16* Cb  = (u16*)wsalloc((size_t)Mq*Dq*2);   // [b,s,d]

  detect_dtype<<<1, 256, 0, stream>>>((const unsigned*)x, flag);
  convert_x<<<dim3(Mq*Dq/8/256), 256, 0, stream>>>(x, xc, flag, Mq*Dq);
  transpose_w<<<dim3(16,16,4), 256, 0, stream>>>(Wq,Wk,Wv,Wo, WqT,WkT,WvT,WoT, flag);
  gemm128<0><<<dim3(24, Mq/128), 512, 0, stream>>>(xc, WqT, Qb,Kb,VTb, nullptr, nullptr, flag);
  flash_attn<<<dim3(16, Bq*Hq), 256, 0, stream>>>(Qb, Kb, VTb, Cb);
  gemm128<1><<<dim3(Dq/128, Mq/128), 512, 0, stream>>>(Cb, WoT, nullptr,nullptr,nullptr, d_out, bo, flag);
}

// Round 7
// 303.981 us; speedup vs baseline: 1.0768x; 1.0768x over previous
//
#include <hip/hip_runtime.h>
#include <hip/hip_bf16.h>

#define Bq 4
#define Sq 2048
#define Dq 1024
#define Hq 16
#define HDq 64
#define Mq (Bq*Sq)   // 8192

typedef unsigned short u16;
typedef __attribute__((ext_vector_type(8))) __bf16 b16x8;
typedef __attribute__((ext_vector_type(4))) float f32x4;
typedef __attribute__((ext_vector_type(4))) unsigned int u32x4;

__device__ inline float bf2f(u16 h){ union{unsigned u; float f;} v; v.u = ((unsigned)h)<<16; return v.f; }
__device__ inline u16 f2bf(float f){ union{float f; unsigned u;} v; v.f=f; unsigned r = v.u + 0x7FFFu + ((v.u>>16)&1u); return (u16)(r>>16); }
__device__ inline u16 truncbf(float f){ union{float f; unsigned u;} v; v.f=f; return (u16)(v.u>>16); }
__device__ inline float ld_elem(const void* p, size_t i, int isf32){
  return isf32 ? ((const float*)p)[i] : bf2f(((const u16*)p)[i]);
}
// async global->LDS, 16B per lane; LDS dest must be wave-uniform-base + lane*16
__device__ inline void ld16(const u16* g, u16* l){
  __builtin_amdgcn_global_load_lds((const __attribute__((address_space(1))) void*)g,
                                   (__attribute__((address_space(3))) void*)l, 16, 0, 0);
}

#if __has_builtin(__builtin_amdgcn_exp2f)
#define EXP2(x) __builtin_amdgcn_exp2f(x)
#else
#define EXP2(x) __expf((x)*0.69314718056f)
#endif
// 0.125 (1/sqrt(64)) * log2(e): folded into Q in the gemm<0> epilogue.
#define SCALE_LOG2E 0.18033688011112042f

// ---- dtype probe: fp32 buffers read as u16 halves -> huge bf16 exponents
__global__ void detect_dtype(const unsigned* __restrict__ x, int* __restrict__ flag){
  __shared__ int cnt;
  if(threadIdx.x==0) cnt=0;
  __syncthreads();
  int local=0;
  for(int i=threadIdx.x;i<2048;i+=256){
    unsigned w = x[i];
    if(((w>>7)&0xFFu)>=0x90u) local++;
    if(((w>>23)&0xFFu)>=0x90u) local++;
  }
  atomicAdd(&cnt, local);
  __syncthreads();
  if(threadIdx.x==0) *flag = (cnt>64) ? 1 : 0;
}

// ---- x -> canonical bf16
__global__ __launch_bounds__(256) void convert_x(const void* __restrict__ x, u16* __restrict__ xc,
                                                 const int* __restrict__ flag, int n){
  const int f = *flag;
  int i = (blockIdx.x*256 + threadIdx.x)*8;
  if(i>=n) return;
  if(f){
    const float* xf=(const float*)x;
    #pragma unroll
    for(int j=0;j<8;j++) xc[i+j] = f2bf(xf[i+j]);
  } else {
    *(u32x4*)&xc[i] = *(const u32x4*)((const u16*)x + i);
  }
}

// ---- weight transpose+convert: W[k][n] -> WT[n][k] bf16
__global__ __launch_bounds__(256) void transpose_w(
    const void* __restrict__ W0, const void* __restrict__ W1,
    const void* __restrict__ W2, const void* __restrict__ W3,
    u16* __restrict__ T0, u16* __restrict__ T1,
    u16* __restrict__ T2, u16* __restrict__ T3,
    const int* __restrict__ flag){
  __shared__ u16 tile[64][65];
  const int f = *flag;
  const int z = blockIdx.z;
  const void* src = (z==0)?W0:(z==1)?W1:(z==2)?W2:W3;
  u16*       dst = (z==0)?T0:(z==1)?T1:(z==2)?T2:T3;
  const int t = threadIdx.x;
  const int k0 = blockIdx.x*64, n0 = blockIdx.y*64;
  #pragma unroll
  for(int r=0;r<16;r++){
    int row = r*4 + (t>>6), col = t&63;
    tile[row][col] = f2bf(ld_elem(src, (size_t)(k0+row)*Dq + n0 + col, f));
  }
  __syncthreads();
  #pragma unroll
  for(int r=0;r<16;r++){
    int row = r*4 + (t>>6), col = t&63;
    dst[(size_t)(n0+row)*Dq + k0 + col] = tile[col][row];
  }
}

// ---------------- GEMM: C = A * Bt^T, BK=64, XOR-swizzled LDS, global_load_lds ----------------
// (r5 structure: measured 103 us, SQ_LDS_BANK_CONFLICT = 0)
// MODE 0: A=xc, Bt = [WqT;WkT;WvT] (N=3072); epilogue: z=n>>10 -> Q (pre-scaled by
//         0.125*log2e for the flash exp2 softmax) / K / VT layouts.
// MODE 1: out-proj + bias, fp32 or bf16 out per flag
template<int MODE>
__global__ __launch_bounds__(256) void gemm128(
    const u16* __restrict__ A, const u16* __restrict__ Bt,
    u16* __restrict__ O0, u16* __restrict__ O1, u16* __restrict__ O2,
    void* __restrict__ Og, const void* __restrict__ bias, const int* __restrict__ flag){
  __shared__ u16 Al[128*64];
  __shared__ u16 Bl[128*64];
  const int f = (MODE==1) ? *flag : 0;
  const int t = threadIdx.x;
  const int lane = t & 63, wave = t >> 6;
  const int quad = lane >> 4, l16 = lane & 15;
  const int wr = wave >> 1, wc = wave & 1;
  const int m0 = blockIdx.y*128, n0 = blockIdx.x*128;

  f32x4 acc[4][4] = {};

  for(int k0=0;k0<Dq;k0+=64){
    #pragma unroll
    for(int r=0;r<4;r++){
      int idx = t + (r<<8);            // slot 0..1023 (16B each)
      int row = idx>>3, g = idx&7;
      int csw = (g ^ (row&7))<<3;      // swizzled source column (elems)
      ld16(&A [(size_t)(m0+row)*Dq + k0 + csw], Al + idx*8);
      ld16(&Bt[(size_t)(n0+row)*Dq + k0 + csw], Bl + idx*8);
    }
    __syncthreads();                   // drain DMA + publish
    #pragma unroll
    for(int ks=0;ks<2;ks++){
      b16x8 af[4], bfr[4];
      #pragma unroll
      for(int i=0;i<4;i++){
        int row = wr*64 + i*16 + l16;
        af[i] = *(const b16x8*)&Al[row*64 + ((((ks<<2)+quad) ^ (row&7))<<3)];
      }
      #pragma unroll
      for(int j=0;j<4;j++){
        int row = wc*64 + j*16 + l16;
        bfr[j] = *(const b16x8*)&Bl[row*64 + ((((ks<<2)+quad) ^ (row&7))<<3)];
      }
      #pragma unroll
      for(int i=0;i<4;i++)
        #pragma unroll
        for(int j=0;j<4;j++)
          acc[i][j] = __builtin_amdgcn_mfma_f32_16x16x32_bf16(af[i], bfr[j], acc[i][j], 0,0,0);
    }
    __syncthreads();
  }

  #pragma unroll
  for(int i=0;i<4;i++){
    #pragma unroll
    for(int j=0;j<4;j++){
      int n = n0 + wc*64 + j*16 + l16;
      #pragma unroll
      for(int r=0;r<4;r++){
        int m = m0 + wr*64 + i*16 + quad*4 + r;   // C/D: row=quad*4+reg, col=l16
        float c = acc[i][j][r];
        if (MODE==1){
          float c2 = c + ld_elem(bias, n, f);
          if (f) ((float*)Og)[(size_t)m*Dq + n] = c2;
          else   ((u16*)Og)[(size_t)m*Dq + n]   = f2bf(c2);
        } else {
          int z = n >> 10, nn = n & 1023;
          int b = m >> 11, s = m & 2047;
          int h = nn >> 6, hd = nn & 63;
          if (z==0)      O0[(((size_t)(b*Hq + h))*Sq + s)*HDq + hd] = f2bf(c*SCALE_LOG2E);
          else if (z==1) O1[(((size_t)(b*Hq + h))*Sq + s)*HDq + hd] = f2bf(c);
          else           O2[(((size_t)(b*Hq + h))*HDq + hd)*Sq + s] = f2bf(c);
        }
      }
    }
  }
}

// ---------------- flash attention v5 ----------------
// v4 + (a) Q pre-scaled in gemm<0> (no per-score multiply), (b) fully-unmasked
// fast path for kt < qt (mask only bites at kt in {qt, qt+1}) -> cmp/select
// removed from ~94% of scores. Structure/LDS unchanged from v4.
__global__ __launch_bounds__(256) void flash_attn(
    const u16* __restrict__ Q, const u16* __restrict__ K,
    const u16* __restrict__ VT, u16* __restrict__ C){
  __shared__ u16 Kt[128*64];    // [key][hd], 8 groups/row swizzled
  __shared__ u16 Vt[64*128];    // [hd][key], 16 groups/row swizzled
  __shared__ u16 Pl[4][16][72]; // per-wave P round-trip (C-layout -> A-layout)
  const int t = threadIdx.x;
  const int lane = t&63, wave = t>>6, quad = lane>>4, l16 = lane&15;
  const int p = blockIdx.x, bh = blockIdx.y;
  const int b = bh >> 4, h = bh & 15;
  const int qt[2] = { p, 31 - p };
  int nk[2];
  #pragma unroll
  for(int tt=0;tt<2;tt++){ int v = qt[tt]+2; nk[tt] = (v<32)?v:32; }
  const int nrounds = (nk[1]+1)>>1;
  const u16* Qh = Q  + (size_t)bh*Sq*HDq;
  const u16* Kh = K  + (size_t)bh*Sq*HDq;
  const u16* Vh = VT + (size_t)bh*HDq*Sq;

  b16x8 aq[2][2];
  #pragma unroll
  for(int tt=0;tt<2;tt++){
    const u16* qp = Qh + (size_t)(qt[tt]*64 + wave*16 + l16)*HDq + quad*8;
    aq[tt][0] = *(const b16x8*)qp;
    aq[tt][1] = *(const b16x8*)(qp + 32);
  }
  b16x8 vone;
  #pragma unroll
  for(int i=0;i<8;i++) vone[i] = (__bf16)1.0f;

  const f32x4 fzero = {0.f,0.f,0.f,0.f};
  f32x4 Oa[2][4]; f32x4 lacc[2];
  #pragma unroll
  for(int tt=0;tt<2;tt++){ lacc[tt]=fzero; for(int j=0;j<4;j++) Oa[tt][j]=fzero; }

  for(int kt2=0; kt2<nrounds; kt2++){
    __syncthreads();
    #pragma unroll
    for(int r=0;r<4;r++){
      int idx = t + (r<<8);            // K slots 0..1023
      int row = idx>>3, g = idx&7;
      int csw = (g ^ (row&7))<<3;
      ld16(Kh + (size_t)(kt2*128+row)*HDq + csw, Kt + idx*8);
    }
    #pragma unroll
    for(int r=0;r<4;r++){
      int idx = t + (r<<8);            // V slots 0..1023
      int row = idx>>4, g = idx&15;    // 64 hd-rows x 16 groups
      int csw = (g ^ (row&15))<<3;
      ld16(Vh + (size_t)row*Sq + (size_t)kt2*128 + csw, Vt + idx*8);
    }
    __syncthreads();

    #pragma unroll
    for(int half=0; half<2; half++){
      const int kt = kt2*2 + half;
      #pragma unroll
      for(int tt=0;tt<2;tt++){
        if (kt >= nk[tt]) continue;            // wave-uniform skip
        const int qq0 = qt[tt]*64;
        f32x4 sc[4];
        #pragma unroll
        for(int jn=0;jn<4;jn++){
          int krow = half*64 + jn*16 + l16;
          const u16* kp = &Kt[krow*64];
          f32x4 s = fzero;
          b16x8 bk0 = *(const b16x8*)&kp[((quad     ^ (krow&7))<<3)];
          b16x8 bk1 = *(const b16x8*)&kp[(((quad+4) ^ (krow&7))<<3)];
          s = __builtin_amdgcn_mfma_f32_16x16x32_bf16(aq[tt][0], bk0, s, 0,0,0);
          s = __builtin_amdgcn_mfma_f32_16x16x32_bf16(aq[tt][1], bk1, s, 0,0,0);
          sc[jn] = s;
        }
        if (kt < qt[tt]) {
          // fully unmasked tile: p = exp2(s) directly (Q carries the scale)
          #pragma unroll
          for(int jn=0;jn<4;jn++)
            #pragma unroll
            for(int r=0;r<4;r++)
              Pl[wave][quad*4+r][jn*16+l16] = truncbf(EXP2(sc[jn][r]));
        } else {
          // boundary tiles kt in {qt, qt+1}: apply causal(+1) mask
          const int qbase = qq0 + wave*16 + quad*4;
          #pragma unroll
          for(int jn=0;jn<4;jn++){
            int kg = kt*64 + jn*16 + l16;
            #pragma unroll
            for(int r=0;r<4;r++){
              float sv = sc[jn][r];
              if (kg > qbase + r + 1) sv = -__builtin_inff();   // tril(k=1): key <= q+1
              Pl[wave][quad*4+r][jn*16+l16] = truncbf(EXP2(sv));
            }
          }
        }
        // O += P V ; l += P . 1   (Pl wave-private: no barrier)
        #pragma unroll
        for(int ks=0;ks<2;ks++){
          b16x8 ap = *(const b16x8*)&Pl[wave][l16][ks*32 + quad*8];
          int glog = half*8 + ks*4 + quad;
          #pragma unroll
          for(int jd=0;jd<4;jd++){
            int hd = jd*16 + l16;
            b16x8 bv = *(const b16x8*)&Vt[hd*128 + ((glog ^ (hd&15))<<3)];
            Oa[tt][jd] = __builtin_amdgcn_mfma_f32_16x16x32_bf16(ap, bv, Oa[tt][jd], 0,0,0);
          }
          lacc[tt] = __builtin_amdgcn_mfma_f32_16x16x32_bf16(ap, vone, lacc[tt], 0,0,0);
        }
      }
    }
  }
  #pragma unroll
  for(int tt=0;tt<2;tt++){
    const int qq0 = qt[tt]*64;
    #pragma unroll
    for(int r=0;r<4;r++){
      int s = qq0 + wave*16 + quad*4 + r;
      float inv = 1.0f / lacc[tt][r];
      #pragma unroll
      for(int jd=0;jd<4;jd++)
        C[((size_t)(b*Sq + s))*Dq + h*HDq + jd*16 + l16] = f2bf(Oa[tt][jd][r]*inv);
    }
  }
}

// ---------------- launch ----------------
extern "C" void kernel_launch(void* const* d_in, const int* in_sizes, int n_in,
                              void* d_out, int out_size, void* d_ws, size_t ws_size,
                              hipStream_t stream){
  const void* x  = d_in[0];
  const void* Wq = d_in[1];
  const void* Wk = d_in[2];
  const void* Wv = d_in[3];
  const void* Wo = d_in[4];
  const void* bo = d_in[5];

  char* ws = (char*)d_ws;
  size_t off = 0;
  auto wsalloc = [&](size_t bytes)->void*{
    void* p = ws + off; off += (bytes + 255) & ~(size_t)255; return p;
  };
  int* flag = (int*)wsalloc(256);
  // WqT/WkT/WvT contiguous: gemm<0> sees one [3072][1024] B^T matrix
  u16* WqT = (u16*)wsalloc((size_t)Dq*Dq*2);
  u16* WkT = (u16*)wsalloc((size_t)Dq*Dq*2);
  u16* WvT = (u16*)wsalloc((size_t)Dq*Dq*2);
  u16* WoT = (u16*)wsalloc((size_t)Dq*Dq*2);
  u16* xc  = (u16*)wsalloc((size_t)Mq*Dq*2);
  u16* Qb  = (u16*)wsalloc((size_t)Mq*Dq*2);   // [b,h,s,hd], pre-scaled
  u16* Kb  = (u16*)wsalloc((size_t)Mq*Dq*2);   // [b,h,s,hd]
  u16* VTb = (u16*)wsalloc((size_t)Mq*Dq*2);   // [b,h,hd,s]
  u16* Cb  = (u16*)wsalloc((size_t)Mq*Dq*2);   // [b,s,d]

  detect_dtype<<<1, 256, 0, stream>>>((const unsigned*)x, flag);
  convert_x<<<dim3(Mq*Dq/8/256), 256, 0, stream>>>(x, xc, flag, Mq*Dq);
  transpose_w<<<dim3(16,16,4), 256, 0, stream>>>(Wq,Wk,Wv,Wo, WqT,WkT,WvT,WoT, flag);
  gemm128<0><<<dim3(24, Mq/128), 256, 0, stream>>>(xc, WqT, Qb,Kb,VTb, nullptr, nullptr, flag);
  flash_attn<<<dim3(16, Bq*Hq), 256, 0, stream>>>(Qb, Kb, VTb, Cb);
  gemm128<1><<<dim3(Dq/128, Mq/128), 256, 0, stream>>>(Cb, WoT, nullptr,nullptr,nullptr, d_out, bo, flag);
}